// Round 9
// baseline (276.931 us; speedup 1.0000x reference)
//
#include <hip/hip_runtime.h>

#define NQ 12
#define NL 6
#define NC 10
#define DIM 4096
#define TPB 512
#define NPASS 24

typedef float v2f __attribute__((ext_vector_type(2)));
#define FMA2(a, b, c) __builtin_elementwise_fma((a), (b), (c))

__device__ __forceinline__ v2f splat2(float v) { v2f r; r.x = v; r.y = v; return r; }

// ---- VOP3P packed-f32 complex butterfly primitives ----
// Coefficient pair c = (k, -k) or (k, k); amplitude a = (re, im).
// SWHL: src0 (hi->low, lo->high), src1 swapped.  NLL: src0 lo broadcast, src1 normal.
// SWLH: src0 (lo->low, hi->high sel swapped), src1 swapped.  NHH: src0 hi broadcast, src1 normal.
#define PK_MUL(d, c, a)    asm("v_pk_mul_f32 %0, %1, %2" : "=v"(d) : "v"(c), "v"(a))
#define PK_FMA_SWHL(d, c, a) asm("v_pk_fma_f32 %0, %1, %2, %0 op_sel:[1,1,0] op_sel_hi:[0,0,1]" : "+v"(d) : "v"(c), "v"(a))
#define PK_FMA_NLL(d, c, a)  asm("v_pk_fma_f32 %0, %1, %2, %0 op_sel:[0,0,0] op_sel_hi:[0,1,1]" : "+v"(d) : "v"(c), "v"(a))
#define PK_FMA_SWLH(d, c, a) asm("v_pk_fma_f32 %0, %1, %2, %0 op_sel:[0,1,0] op_sel_hi:[1,0,1]" : "+v"(d) : "v"(c), "v"(a))
#define PK_FMA_NHH(d, c, a)  asm("v_pk_fma_f32 %0, %1, %2, %0 op_sel:[1,0,0] op_sel_hi:[1,1,1]" : "+v"(d) : "v"(c), "v"(a))

struct PassA { unsigned short Acol[9]; unsigned short svo4[8]; unsigned short w[3]; };
struct QCArgs {
    PassA P[NPASS];
    unsigned short Gcol0[9];
    unsigned short vc0[8];
    unsigned short wq[NQ];
    unsigned char  tab[NQ];
};

__global__ __launch_bounds__(TPB, 8) void qsim_k(
    const float* __restrict__ x, const float* __restrict__ qp,
    const float* __restrict__ fcw, const float* __restrict__ fcb,
    float* __restrict__ out, int B, QCArgs K)
{
    __shared__ v2f stv[DIM];             // (re, im) per amp, layout T*m  -> 32 KB
    __shared__ float4 gmat[NL * NQ];     // (ur, ui, wr, wi)
    __shared__ float csn[NQ], snn[NQ];
    __shared__ float zred[8 * NQ];
    __shared__ float zfin[NQ];

    const unsigned tid = threadIdx.x;
    const int blk = blockIdx.x;

    if (tid < NL * NQ) {
        float phi = qp[tid * 3 + 0];
        float th  = qp[tid * 3 + 1];
        float om  = qp[tid * 3 + 2];
        float st_, ct, sa, ca, sb, cb;
        sincosf(0.5f * th, &st_, &ct);
        sincosf(0.5f * (phi + om), &sa, &ca);
        sincosf(0.5f * (phi - om), &sb, &cb);
        gmat[tid] = make_float4(ca * ct, -sa * ct, cb * st_, -sb * st_);
    }
    if (tid < NQ) {
        float s, c;
        sincosf(0.5f * x[(size_t)blk * NQ + tid], &s, &c);
        csn[tid] = c; snn[tid] = s;
    }
    __syncthreads();

    // ---- init product state PRE-LOOP via pass-0 map; bit p of m <-> qubit 11-p ----
    {
        float csr[NQ], snr[NQ];
        #pragma unroll
        for (int p = 0; p < NQ; ++p) { csr[p] = csn[11 - p]; snr[p] = snn[11 - p]; }
        unsigned G = 0, A0 = 0;
        #pragma unroll
        for (int b2 = 0; b2 < 9; ++b2) {
            unsigned mneg = (unsigned)(-(int)((tid >> b2) & 1u));
            G  ^= mneg & (unsigned)K.Gcol0[b2];
            A0 ^= mneg & (unsigned)K.P[0].Acol[b2];
        }
        #pragma unroll
        for (int s = 0; s < 8; ++s) {
            unsigned idx = G ^ (unsigned)K.vc0[s];
            float amp = 1.0f;
            #pragma unroll
            for (int p = 0; p < NQ; ++p)
                amp *= ((idx >> p) & 1) ? snr[p] : csr[p];
            unsigned ad0 = A0 ^ (unsigned)K.P[0].svo4[s];
            v2f a; a.x = amp; a.y = 0.0f;
            *(v2f*)((char*)stv + ad0) = a;
        }
    }

    v2f am[8];

    // ---- 24 passes, 3 gates each; in-place per-thread cosets; 1 barrier/pass ----
    #pragma unroll 1
    for (int k = 0; k < NPASS; ++k) {
        __syncthreads();
        const PassA& P = K.P[k];

        unsigned A = 0;
        #pragma unroll
        for (int b2 = 0; b2 < 9; ++b2) {
            unsigned mneg = (unsigned)(-(int)((tid >> b2) & 1u));
            A ^= mneg & (unsigned)P.Acol[b2];
        }
        unsigned ad[8];
        #pragma unroll
        for (int s = 0; s < 8; ++s) {
            ad[s] = A ^ (unsigned)P.svo4[s];
            am[s] = *(const v2f*)((const char*)stv + ad[s]);
        }

        const int gb = (k >> 2) * NQ + (k & 3) * 3;
        #pragma unroll
        for (int j = 0; j < 3; ++j) {
            float4 gq = gmat[gb + j];
            unsigned sg = (unsigned)(__popc((unsigned)P.w[j] & tid) & 1) << 31;
            unsigned uia = __float_as_uint(gq.y) ^ sg;
            unsigned wra = __float_as_uint(gq.z) ^ sg ^ 0x80000000u;
            unsigned wii = __float_as_uint(gq.w);
            v2f Cu, Cuia, Cwra, Cwi;
            Cu.x = gq.x;                      Cu.y = gq.x;
            Cuia.x = __uint_as_float(uia);    Cuia.y = __uint_as_float(uia ^ 0x80000000u);
            Cwra.x = __uint_as_float(wra);    Cwra.y = __uint_as_float(wra ^ 0x80000000u);
            Cwi.x  = __uint_as_float(wii);    Cwi.y  = __uint_as_float(wii ^ 0x80000000u);
            #pragma unroll
            for (int s = 0; s < 8; ++s) {
                if (!(s & (1 << j))) {
                    const int sb = s | (1 << j);
                    v2f a0 = am[s], a1 = am[sb];
                    v2f o0, o1;
                    // o0 = (ur*a0r - uia*a0i + wra*a1r - wi*a1i,
                    //       ur*a0i + uia*a0r + wra*a1i + wi*a1r)
                    PK_MUL(o0, Cu, a0);
                    PK_FMA_SWHL(o0, Cuia, a0);
                    PK_FMA_NLL(o0, Cwra, a1);
                    PK_FMA_SWHL(o0, Cwi, a1);
                    // o1 = (ur*a1r + uia*a1i - wra*a0r - wi*a0i,
                    //       ur*a1i - uia*a1r - wra*a0i + wi*a0r)
                    PK_MUL(o1, Cu, a1);
                    PK_FMA_SWLH(o1, Cuia, a1);
                    PK_FMA_NHH(o1, Cwra, a0);
                    PK_FMA_SWHL(o1, Cwi, a0);
                    am[s] = o0; am[sb] = o1;
                }
            }
        }

        if (k < NPASS - 1) {
            #pragma unroll
            for (int s = 0; s < 8; ++s)
                *(v2f*)((char*)stv + ad[s]) = am[s];
        }
    }

    // ---- PauliZ expvals from final-pass registers ----
    float p2[8];
    #pragma unroll
    for (int s = 0; s < 8; ++s) p2[s] = fmaf(am[s].x, am[s].x, am[s].y * am[s].y);

    float z[NQ];
    #pragma unroll
    for (int q = 0; q < NQ; ++q) {
        float base = (__popc((unsigned)K.wq[q] & tid) & 1) ? -1.0f : 1.0f;
        float acc = 0.0f;
        #pragma unroll
        for (int s = 0; s < 8; ++s) {
            float sgn = ((K.tab[q] >> s) & 1) ? -base : base;
            acc = fmaf(sgn, p2[s], acc);
        }
        z[q] = acc;
    }

    #pragma unroll
    for (int q = 0; q < NQ; ++q) {
        float v = z[q];
        #pragma unroll
        for (int o = 1; o < 64; o <<= 1) v += __shfl_xor(v, o, 64);
        z[q] = v;
    }
    const int lane = tid & 63, wv = tid >> 6;
    if (lane == 0) {
        #pragma unroll
        for (int q = 0; q < NQ; ++q) zred[wv * NQ + q] = z[q];
    }
    __syncthreads();
    if (tid < NQ) {
        float acc = zred[tid];
        #pragma unroll
        for (int w2 = 1; w2 < 8; ++w2) acc += zred[w2 * NQ + tid];
        zfin[tid] = acc;
    }
    __syncthreads();

    if (tid < NC) {
        float acc = fcb[tid];
        #pragma unroll
        for (int q = 0; q < NQ; ++q) acc = fmaf(fcw[tid * NQ + q], zfin[q], acc);
        out[(size_t)blk * NC + tid] = acc;
    }
}

// ---------------- host: GF(2) circuit algebra + per-16-lane conflict-free layout ----------------
static void inv12(const unsigned Ain[12], unsigned Ai[12]) {
    unsigned M[12], I[12];
    for (int i = 0; i < 12; ++i) { M[i] = Ain[i]; I[i] = 1u << i; }
    for (int c = 0; c < 12; ++c) {
        int pr = -1;
        for (int r2 = c; r2 < 12; ++r2) if ((M[r2] >> c) & 1u) { pr = r2; break; }
        unsigned tm = M[c]; M[c] = M[pr]; M[pr] = tm;
        tm = I[c]; I[c] = I[pr]; I[pr] = tm;
        for (int r2 = 0; r2 < 12; ++r2)
            if (r2 != c && ((M[r2] >> c) & 1u)) { M[r2] ^= M[c]; I[r2] ^= I[c]; }
    }
    for (int i = 0; i < 12; ++i) Ai[i] = I[i];
}

static unsigned lcg(unsigned& s) { s = s * 1664525u + 1013904223u; return s >> 8; }
static int pc(unsigned v) { return __builtin_popcount(v); }

static int rank_rows(const unsigned* rows, int n) {
    unsigned ech[16], low[16]; int rk = 0;
    for (int i = 0; i < n; ++i) {
        unsigned v = rows[i];
        for (int k2 = 0; k2 < rk; ++k2) if (v & low[k2]) v ^= ech[k2];
        if (v) { ech[rk] = v; low[rk] = v & (0u - v); ++rk; }
    }
    return rk;
}

extern "C" void kernel_launch(void* const* d_in, const int* in_sizes, int n_in,
                              void* d_out, int out_size, void* d_ws, size_t ws_size,
                              hipStream_t stream) {
    const float* x    = (const float*)d_in[0];
    const float* qp   = (const float*)d_in[1];
    const float* fc_w = (const float*)d_in[2];
    const float* fc_b = (const float*)d_in[3];
    float* out = (float*)d_out;
    int B = in_sizes[0] / NQ;

    unsigned L[12];
    for (int i = 0; i < 12; ++i) L[i] = 1u << i;

    static unsigned vAll[NPASS][3], rAll[NPASS][3], vcAll[NPASS][8];
    static int posAll[NPASS][9];

    for (int l = 0; l < NL; ++l) {
        unsigned Linv[12];
        inv12(L, Linv);
        for (int m = 0; m < 4; ++m) {
            int k = l * 4 + m;
            for (int j = 0; j < 3; ++j) {
                int q = 3 * m + j, bb = 11 - q;
                rAll[k][j] = L[bb];
                unsigned vv = 0;
                for (int i = 0; i < 12; ++i) vv |= ((Linv[i] >> bb) & 1u) << i;
                vAll[k][j] = vv;
            }
            unsigned w[3] = { vAll[k][0], vAll[k][1], vAll[k][2] };
            int piv[3];
            for (int j = 0; j < 3; ++j) {
                for (int k2 = 0; k2 < j; ++k2)
                    if ((w[j] >> piv[k2]) & 1u) w[j] ^= w[k2];
                piv[j] = __builtin_ctz(w[j]);
            }
            bool ispiv[12] = {};
            for (int j = 0; j < 3; ++j) ispiv[piv[j]] = true;
            int c = 0;
            for (int pos = 0; pos < 12; ++pos)
                if (!ispiv[pos]) posAll[k][c++] = pos;
            for (int s = 0; s < 8; ++s) {
                unsigned vc = 0;
                for (int j = 0; j < 3; ++j) if ((s >> j) & 1) vc ^= vAll[k][j];
                vcAll[k][s] = vc;
            }
        }
        int rr = l + 1;
        for (int q = 0; q < 12; ++q) {
            int tq = (q + rr) % 12;
            L[11 - tq] ^= L[11 - q];
        }
    }
    unsigned rfin[12];
    for (int q = 0; q < 12; ++q) rfin[q] = L[11 - q];

    // ---- label search: nonzero 4-bit label per position; every pass's 9 positions must span GF(2)^4 ----
    unsigned labels[12];
    unsigned seed = 0xC0FFEE1u;
    bool okL = false;
    for (int att = 0; att < 500000 && !okL; ++att) {
        for (int i = 0; i < 12; ++i) labels[i] = 1u + (lcg(seed) % 15u);
        okL = true;
        for (int k = 0; k < NPASS && okL; ++k) {
            unsigned vals[9];
            for (int b = 0; b < 9; ++b) vals[b] = labels[posAll[k][b]];
            okL = (rank_rows(vals, 9) >= 4);
        }
    }

    // ---- per-pass: move an independent-label quad to thread bits 0..3 ----
    for (int k = 0; k < NPASS; ++k) {
        int used[9] = {};
        int chosen[4]; int nch = 0;
        unsigned ech[4], low[4]; int rk = 0;
        for (int b = 0; b < 9 && nch < 4; ++b) {
            unsigned v = labels[posAll[k][b]];
            for (int j = 0; j < rk; ++j) if (v & low[j]) v ^= ech[j];
            if (v) { ech[rk] = v; low[rk] = v & (0u - v); ++rk; chosen[nch++] = b; used[b] = 1; }
        }
        for (int b = 0; b < 9 && nch < 4; ++b)
            if (!used[b]) { chosen[nch++] = b; used[b] = 1; }
        int outp[9]; int c2 = 0;
        for (int j = 0; j < nch; ++j) outp[c2++] = posAll[k][chosen[j]];
        for (int b = 0; b < 9; ++b) if (!used[b]) outp[c2++] = posAll[k][b];
        for (int b = 0; b < 9; ++b) posAll[k][b] = outp[b];
    }

    // ---- layout matrix T: rows 0..3 from labels, extend to full rank ----
    unsigned Trow[12];
    for (int i = 0; i < 4; ++i) {
        unsigned r = 0;
        for (int pos = 0; pos < 12; ++pos) r |= ((labels[pos] >> i) & 1u) << pos;
        Trow[i] = r;
    }
    {
        unsigned ech[12], low[12]; int rk = 0;
        auto addrow = [&](unsigned vr) -> bool {
            unsigned vv = vr;
            for (int i = 0; i < rk; ++i) if (vv & low[i]) vv ^= ech[i];
            if (!vv) return false;
            ech[rk] = vv; low[rk] = vv & (0u - vv); ++rk;
            return true;
        };
        addrow(Trow[0]); addrow(Trow[1]); addrow(Trow[2]); addrow(Trow[3]);
        int idx = 4, tries = 0;
        while (idx < 12 && tries < 100000) {
            unsigned rr2 = lcg(seed) & 4095u;
            if (rr2 && addrow(rr2)) Trow[idx++] = rr2;
            ++tries;
        }
        for (int i = 0; i < 12 && idx < 12; ++i)
            if (addrow(1u << i)) Trow[idx++] = 1u << i;
    }
    unsigned Tcol[12];
    for (int pos = 0; pos < 12; ++pos) {
        unsigned o = 0;
        for (int i = 0; i < 12; ++i) o |= ((Trow[i] >> pos) & 1u) << i;
        Tcol[pos] = o;
    }
    auto Tmap = [&](unsigned m) -> unsigned {
        unsigned o = 0;
        for (int i = 0; i < 12; ++i) o |= (unsigned)(pc(Trow[i] & m) & 1) << i;
        return o;
    };

    QCArgs K;
    for (int k = 0; k < NPASS; ++k) {
        for (int b = 0; b < 9; ++b)
            K.P[k].Acol[b] = (unsigned short)(Tcol[posAll[k][b]] << 3);
        for (int s = 0; s < 8; ++s)
            K.P[k].svo4[s] = (unsigned short)(Tmap(vcAll[k][s]) << 3);
        for (int j = 0; j < 3; ++j) {
            unsigned ws = 0;
            for (int b = 0; b < 9; ++b)
                ws |= ((rAll[k][j] >> posAll[k][b]) & 1u) << b;
            K.P[k].w[j] = (unsigned short)ws;
        }
    }
    for (int b = 0; b < 9; ++b) K.Gcol0[b] = (unsigned short)(1u << posAll[0][b]);
    for (int s = 0; s < 8; ++s) K.vc0[s] = (unsigned short)vcAll[0][s];
    for (int q = 0; q < NQ; ++q) {
        unsigned ws = 0;
        for (int b = 0; b < 9; ++b)
            ws |= ((rfin[q] >> posAll[NPASS - 1][b]) & 1u) << b;
        K.wq[q] = (unsigned short)ws;
        unsigned tb = 0;
        for (int s = 0; s < 8; ++s)
            tb |= (unsigned)(pc(rfin[q] & vcAll[NPASS - 1][s]) & 1) << s;
        K.tab[q] = (unsigned char)tb;
    }

    qsim_k<<<B, TPB, 0, stream>>>(x, qp, fc_w, fc_b, out, B, K);
}

// Round 10
// 227.098 us; speedup vs baseline: 1.2194x; 1.2194x over previous
//
#include <hip/hip_runtime.h>

#define NQ 12
#define NL 6
#define NC 10
#define DIM 4096
#define TPB 256
#define NPASS 18

typedef float v2f __attribute__((ext_vector_type(2)));
#define FMA2(a, b, c) __builtin_elementwise_fma((a), (b), (c))

// ---- VOP3P packed-f32 butterfly primitives (static op_sel + neg; zero coefficient prep) ----
// c = (lo,hi) coefficient pair; a = (re,im) amplitude.
// o0 = u*a0 - conj(w)*a1 ; o1 = w*a0 + conj(u)*a1 with Pa=(ur,ui), Pb=(wr,wi)
#define PK_MUL_L(d, c, a)       asm("v_pk_mul_f32 %0, %1, %2 op_sel:[0,0] op_sel_hi:[0,1]" : "=v"(d) : "v"(c), "v"(a))
#define PK_FMA_HSW_NL(d, c, a)  asm("v_pk_fma_f32 %0, %1, %2, %0 op_sel:[1,1,0] op_sel_hi:[1,0,1] neg_lo:[0,1,0]" : "+v"(d) : "v"(c), "v"(a))
#define PK_FMA_L_NB(d, c, a)    asm("v_pk_fma_f32 %0, %1, %2, %0 op_sel:[0,0,0] op_sel_hi:[0,1,1] neg_lo:[1,0,0] neg_hi:[1,0,0]" : "+v"(d) : "v"(c), "v"(a))
#define PK_FMA_L(d, c, a)       asm("v_pk_fma_f32 %0, %1, %2, %0 op_sel:[0,0,0] op_sel_hi:[0,1,1]" : "+v"(d) : "v"(c), "v"(a))
#define PK_FMA_HSW_NH(d, c, a)  asm("v_pk_fma_f32 %0, %1, %2, %0 op_sel:[1,1,0] op_sel_hi:[1,0,1] neg_hi:[0,1,0]" : "+v"(d) : "v"(c), "v"(a))

struct PassA { unsigned short Acol[8]; unsigned short svo[16]; };
struct QCArgs {
    PassA P[NPASS];
    unsigned short Gcol0[8];    // logical-index columns for init (sign-folded)
    unsigned short vc0l[16];    // logical coset offsets for init
    unsigned short wq[NQ];      // expval sign columns over 8 tid bits (sign-folded)
    unsigned short tab[NQ];     // expval per-slot sign bits (16 slots)
};

__global__ __launch_bounds__(TPB, 4) void qsim_k(
    const float* __restrict__ x, const float* __restrict__ qp,
    const float* __restrict__ fcw, const float* __restrict__ fcb,
    float* __restrict__ out, int B, QCArgs K)
{
    __shared__ v2f stv[DIM];             // (re, im), layout T*m  -> 32 KB
    __shared__ float4 gmat[NL * NQ];     // (ur, ui, wr, wi) raw
    __shared__ float csn[NQ], snn[NQ];
    __shared__ float zred[4 * NQ];
    __shared__ float zfin[NQ];

    const unsigned tid = threadIdx.x;
    const int blk = blockIdx.x;

    if (tid < NL * NQ) {
        float phi = qp[tid * 3 + 0];
        float th  = qp[tid * 3 + 1];
        float om  = qp[tid * 3 + 2];
        float st_, ct, sa, ca, sb, cb;
        sincosf(0.5f * th, &st_, &ct);
        sincosf(0.5f * (phi + om), &sa, &ca);
        sincosf(0.5f * (phi - om), &sb, &cb);
        gmat[tid] = make_float4(ca * ct, -sa * ct, cb * st_, -sb * st_);
    }
    if (tid < NQ) {
        float s, c;
        sincosf(0.5f * x[(size_t)blk * NQ + tid], &s, &c);
        csn[tid] = c; snn[tid] = s;
    }
    __syncthreads();

    // per-thread bit masks, cached
    unsigned mneg[8];
    #pragma unroll
    for (int b = 0; b < 8; ++b) mneg[b] = (unsigned)(-(int)((tid >> b) & 1u));

    // ---- init product state via pass-0 map; logical bit p <-> qubit 11-p ----
    {
        float csr[NQ], snr[NQ];
        #pragma unroll
        for (int p = 0; p < NQ; ++p) { csr[p] = csn[11 - p]; snr[p] = snn[11 - p]; }
        unsigned G = 0, A0 = 0;
        #pragma unroll
        for (int b = 0; b < 8; ++b) {
            G  ^= mneg[b] & (unsigned)K.Gcol0[b];
            A0 ^= mneg[b] & (unsigned)K.P[0].Acol[b];
        }
        #pragma unroll
        for (int s = 0; s < 16; ++s) {
            unsigned idx = G ^ (unsigned)K.vc0l[s];
            float amp = 1.0f;
            #pragma unroll
            for (int p = 0; p < NQ; ++p)
                amp *= ((idx >> p) & 1) ? snr[p] : csr[p];
            v2f a; a.x = amp; a.y = 0.0f;
            *(v2f*)((char*)stv + (A0 ^ (unsigned)K.P[0].svo[s])) = a;
        }
    }

    v2f am[16];
    unsigned ad[16];

    // ---- 18 passes, 4 gates each; in-place per-thread 16-amp cosets; 1 barrier/pass ----
    #pragma unroll 1
    for (int k = 0; k < NPASS; ++k) {
        __syncthreads();
        const PassA& P = K.P[k];

        unsigned A = 0;
        #pragma unroll
        for (int b = 0; b < 8; ++b) A ^= mneg[b] & (unsigned)P.Acol[b];
        #pragma unroll
        for (int s = 0; s < 16; ++s) {
            ad[s] = A ^ (unsigned)P.svo[s];
            am[s] = *(const v2f*)((const char*)stv + ad[s]);
        }

        const int gb = (k / 3) * NQ + (k % 3) * 4;
        #pragma unroll
        for (int j = 0; j < 4; ++j) {
            float4 gq = gmat[gb + j];
            v2f Pa, Pb;
            Pa.x = gq.x; Pa.y = gq.y;   // (ur, ui)
            Pb.x = gq.z; Pb.y = gq.w;   // (wr, wi)
            #pragma unroll
            for (int s = 0; s < 16; ++s) {
                if (!(s & (1 << j))) {
                    const int sb = s | (1 << j);
                    v2f a0 = am[s], a1 = am[sb];
                    v2f o0, o1;
                    // o0 = (ur*a0r - ui*a0i - wr*a1r - wi*a1i,
                    //       ur*a0i + ui*a0r - wr*a1i + wi*a1r)
                    PK_MUL_L(o0, Pa, a0);
                    PK_FMA_HSW_NL(o0, Pa, a0);
                    PK_FMA_L_NB(o0, Pb, a1);
                    PK_FMA_HSW_NL(o0, Pb, a1);
                    // o1 = (wr*a0r - wi*a0i + ur*a1r + ui*a1i,
                    //       wr*a0i + wi*a0r + ur*a1i - ui*a1r)
                    PK_MUL_L(o1, Pb, a0);
                    PK_FMA_HSW_NL(o1, Pb, a0);
                    PK_FMA_L(o1, Pa, a1);
                    PK_FMA_HSW_NH(o1, Pa, a1);
                    am[s] = o0; am[sb] = o1;
                }
            }
        }

        if (k < NPASS - 1) {
            #pragma unroll
            for (int s = 0; s < 16; ++s)
                *(v2f*)((char*)stv + ad[s]) = am[s];
        }
    }

    // ---- PauliZ expvals from final-pass registers ----
    float p2[16];
    #pragma unroll
    for (int s = 0; s < 16; ++s) p2[s] = fmaf(am[s].x, am[s].x, am[s].y * am[s].y);

    float z[NQ];
    #pragma unroll
    for (int q = 0; q < NQ; ++q) {
        float base = (__popc((unsigned)K.wq[q] & tid) & 1) ? -1.0f : 1.0f;
        float acc = 0.0f;
        #pragma unroll
        for (int s = 0; s < 16; ++s) {
            float sgn = ((K.tab[q] >> s) & 1) ? -base : base;
            acc = fmaf(sgn, p2[s], acc);
        }
        z[q] = acc;
    }

    #pragma unroll
    for (int q = 0; q < NQ; ++q) {
        float v = z[q];
        #pragma unroll
        for (int o = 1; o < 64; o <<= 1) v += __shfl_xor(v, o, 64);
        z[q] = v;
    }
    const int lane = tid & 63, wv = tid >> 6;
    if (lane == 0) {
        #pragma unroll
        for (int q = 0; q < NQ; ++q) zred[wv * NQ + q] = z[q];
    }
    __syncthreads();
    if (tid < NQ) {
        float acc = zred[tid] + zred[NQ + tid] + zred[2 * NQ + tid] + zred[3 * NQ + tid];
        zfin[tid] = acc;
    }
    __syncthreads();

    if (tid < NC) {
        float acc = fcb[tid];
        #pragma unroll
        for (int q = 0; q < NQ; ++q) acc = fmaf(fcw[tid * NQ + q], zfin[q], acc);
        out[(size_t)blk * NC + tid] = acc;
    }
}

// ---------------- host: GF(2) circuit algebra + sign folding + conflict-free layout ----------------
static void inv12(const unsigned Ain[12], unsigned Ai[12]) {
    unsigned M[12], I[12];
    for (int i = 0; i < 12; ++i) { M[i] = Ain[i]; I[i] = 1u << i; }
    for (int c = 0; c < 12; ++c) {
        int pr = -1;
        for (int r2 = c; r2 < 12; ++r2) if ((M[r2] >> c) & 1u) { pr = r2; break; }
        unsigned tm = M[c]; M[c] = M[pr]; M[pr] = tm;
        tm = I[c]; I[c] = I[pr]; I[pr] = tm;
        for (int r2 = 0; r2 < 12; ++r2)
            if (r2 != c && ((M[r2] >> c) & 1u)) { M[r2] ^= M[c]; I[r2] ^= I[c]; }
    }
    for (int i = 0; i < 12; ++i) Ai[i] = I[i];
}

static unsigned lcg(unsigned& s) { s = s * 1664525u + 1013904223u; return s >> 8; }
static int pc(unsigned v) { return __builtin_popcount(v); }

extern "C" void kernel_launch(void* const* d_in, const int* in_sizes, int n_in,
                              void* d_out, int out_size, void* d_ws, size_t ws_size,
                              hipStream_t stream) {
    const float* x    = (const float*)d_in[0];
    const float* qp   = (const float*)d_in[1];
    const float* fc_w = (const float*)d_in[2];
    const float* fc_b = (const float*)d_in[3];
    float* out = (float*)d_out;
    int B = in_sizes[0] / NQ;

    unsigned L[12];
    for (int i = 0; i < 12; ++i) L[i] = 1u << i;

    static unsigned vAll[NPASS][4], rAll[NPASS][4], vcAll[NPASS][16];
    static int posAll[NPASS][8];

    for (int l = 0; l < NL; ++l) {
        unsigned Linv[12];
        inv12(L, Linv);
        for (int m = 0; m < 3; ++m) {
            int k = l * 3 + m;
            for (int j = 0; j < 4; ++j) {
                int qq = 4 * m + j, bb = 11 - qq;
                rAll[k][j] = L[bb];
                unsigned vv = 0;
                for (int i = 0; i < 12; ++i) vv |= ((Linv[i] >> bb) & 1u) << i;
                vAll[k][j] = vv;
            }
            // pivot positions of {v0..v3}
            unsigned w[4];
            int piv[4];
            for (int j = 0; j < 4; ++j) {
                w[j] = vAll[k][j];
                for (int k2 = 0; k2 < j; ++k2)
                    if ((w[j] >> piv[k2]) & 1u) w[j] ^= w[k2];
                piv[j] = __builtin_ctz(w[j]);
            }
            bool ispiv[12] = {};
            for (int j = 0; j < 4; ++j) ispiv[piv[j]] = true;
            int c = 0;
            for (int pos = 0; pos < 12; ++pos)
                if (!ispiv[pos]) posAll[k][c++] = pos;
            for (int s = 0; s < 16; ++s) {
                unsigned vc = 0;
                for (int j = 0; j < 4; ++j) if ((s >> j) & 1) vc ^= vAll[k][j];
                vcAll[k][s] = vc;
            }
        }
        int rr = l + 1;
        for (int q = 0; q < 12; ++q) {
            int tq = (q + rr) % 12;
            L[11 - tq] ^= L[11 - q];
        }
    }
    unsigned rfin[12];
    for (int q = 0; q < 12; ++q) rfin[q] = L[11 - q];

    // ---- label search with SIGN-FOLDED conflict condition ----
    // folded label of position p in pass k: flab = labels[p] ^ XOR_j [r_j(p)] * Lab(v_j)
    unsigned labels[12];
    unsigned seed = 0xBEEF123u;
    bool okAll = false;
    for (int att = 0; att < 400000 && !okAll; ++att) {
        for (int i = 0; i < 12; ++i) labels[i] = 1u + (lcg(seed) % 15u);
        okAll = true;
        for (int k = 0; k < NPASS && okAll; ++k) {
            unsigned Labj[4];
            for (int j = 0; j < 4; ++j) {
                unsigned lj = 0, v = vAll[k][j];
                for (int pos = 0; pos < 12; ++pos) if ((v >> pos) & 1u) lj ^= labels[pos];
                Labj[j] = lj;
            }
            // greedy: find 4 independent folded labels among the 8 free positions
            unsigned ech[4], low[4]; int rk = 0;
            for (int b = 0; b < 8 && rk < 4; ++b) {
                int p = posAll[k][b];
                unsigned f = labels[p];
                for (int j = 0; j < 4; ++j) if ((rAll[k][j] >> p) & 1u) f ^= Labj[j];
                unsigned vv = f & 15u;
                for (int i = 0; i < rk; ++i) if (vv & low[i]) vv ^= ech[i];
                if (vv) { ech[rk] = vv; low[rk] = vv & (0u - vv); ++rk; }
            }
            okAll = (rk == 4);
        }
    }

    // per-pass: reorder so 4 independent-folded-label positions occupy thread bits 0..3
    for (int k = 0; k < NPASS; ++k) {
        unsigned Labj[4];
        for (int j = 0; j < 4; ++j) {
            unsigned lj = 0, v = vAll[k][j];
            for (int pos = 0; pos < 12; ++pos) if ((v >> pos) & 1u) lj ^= labels[pos];
            Labj[j] = lj;
        }
        unsigned flab[8];
        for (int b = 0; b < 8; ++b) {
            int p = posAll[k][b];
            unsigned f = labels[p];
            for (int j = 0; j < 4; ++j) if ((rAll[k][j] >> p) & 1u) f ^= Labj[j];
            flab[b] = f & 15u;
        }
        int used[8] = {}, chosen[4], nch = 0;
        unsigned ech[4], low[4]; int rk = 0;
        for (int b = 0; b < 8 && nch < 4; ++b) {
            unsigned vv = flab[b];
            for (int i = 0; i < rk; ++i) if (vv & low[i]) vv ^= ech[i];
            if (vv) { ech[rk] = vv; low[rk] = vv & (0u - vv); ++rk; chosen[nch++] = b; used[b] = 1; }
        }
        for (int b = 0; b < 8 && nch < 4; ++b)
            if (!used[b]) { chosen[nch++] = b; used[b] = 1; }
        int outp[8]; int c2 = 0;
        for (int j = 0; j < nch; ++j) outp[c2++] = posAll[k][chosen[j]];
        for (int b = 0; b < 8; ++b) if (!used[b]) outp[c2++] = posAll[k][b];
        for (int b = 0; b < 8; ++b) posAll[k][b] = outp[b];
    }

    // ---- layout matrix T: rows 0..3 = label bit-planes, extend to full rank ----
    unsigned Trow[12];
    for (int i = 0; i < 4; ++i) {
        unsigned r = 0;
        for (int pos = 0; pos < 12; ++pos) r |= ((labels[pos] >> i) & 1u) << pos;
        Trow[i] = r;
    }
    {
        unsigned ech[12], low[12]; int rk = 0;
        auto addrow = [&](unsigned vr) -> bool {
            unsigned vv = vr;
            for (int i = 0; i < rk; ++i) if (vv & low[i]) vv ^= ech[i];
            if (!vv) return false;
            ech[rk] = vv; low[rk] = vv & (0u - vv); ++rk;
            return true;
        };
        addrow(Trow[0]); addrow(Trow[1]); addrow(Trow[2]); addrow(Trow[3]);
        int idx = 4, tries = 0;
        while (idx < 12 && tries < 100000) {
            unsigned rr2 = lcg(seed) & 4095u;
            if (rr2 && addrow(rr2)) Trow[idx++] = rr2;
            ++tries;
        }
        for (int i = 0; i < 12 && idx < 12; ++i)
            if (addrow(1u << i)) Trow[idx++] = 1u << i;
    }
    unsigned Tcol[12];
    for (int pos = 0; pos < 12; ++pos) {
        unsigned o = 0;
        for (int i = 0; i < 12; ++i) o |= ((Trow[i] >> pos) & 1u) << i;
        Tcol[pos] = o;
    }
    auto Tmap = [&](unsigned m) -> unsigned {
        unsigned o = 0;
        for (int i = 0; i < 12; ++i) o |= (unsigned)(pc(Trow[i] & m) & 1) << i;
        return o;
    };

    QCArgs K;
    for (int k = 0; k < NPASS; ++k) {
        unsigned Dt[4];
        for (int j = 0; j < 4; ++j) Dt[j] = Tmap(vAll[k][j]);
        for (int b = 0; b < 8; ++b) {
            int p = posAll[k][b];
            unsigned col = Tcol[p];
            for (int j = 0; j < 4; ++j)
                if ((rAll[k][j] >> p) & 1u) col ^= Dt[j];   // sign fold
            K.P[k].Acol[b] = (unsigned short)(col << 3);
        }
        for (int s = 0; s < 16; ++s)
            K.P[k].svo[s] = (unsigned short)(Tmap(vcAll[k][s]) << 3);
    }
    // init tables (logical space, pass-0 sign-folded)
    for (int b = 0; b < 8; ++b) {
        int p = posAll[0][b];
        unsigned g = 1u << p;
        for (int j = 0; j < 4; ++j)
            if ((rAll[0][j] >> p) & 1u) g ^= vAll[0][j];
        K.Gcol0[b] = (unsigned short)g;
    }
    for (int s = 0; s < 16; ++s) K.vc0l[s] = (unsigned short)vcAll[0][s];
    // expval tables (last pass, sign-folded)
    const int kl = NPASS - 1;
    for (int q = 0; q < NQ; ++q) {
        unsigned ws = 0;
        for (int b = 0; b < 8; ++b) {
            int p = posAll[kl][b];
            unsigned bit = (rfin[q] >> p) & 1u;
            for (int j = 0; j < 4; ++j)
                bit ^= ((rAll[kl][j] >> p) & 1u) & (unsigned)(pc(rfin[q] & vAll[kl][j]) & 1);
            ws |= bit << b;
        }
        K.wq[q] = (unsigned short)ws;
        unsigned tb = 0;
        for (int s = 0; s < 16; ++s)
            tb |= (unsigned)(pc(rfin[q] & vcAll[kl][s]) & 1) << s;
        K.tab[q] = (unsigned short)tb;
    }

    qsim_k<<<B, TPB, 0, stream>>>(x, qp, fc_w, fc_b, out, B, K);
}